// Round 1
// 1174.730 us; speedup vs baseline: 1.3443x; 1.3443x over previous
//
#include <hip/hip_runtime.h>
#include <hip/hip_bf16.h>
#include <math.h>

// Problem dims (fixed)
#define BATCHN   4
#define CHN      8
#define SEQ      1024
#define DMODEL   512
#define DSTATE   16
#define DCONV    4
#define DINNER   1024
#define DTRANK   32
#define NROWS    32768          // BATCH*CH*SEQ
#define XD       64             // DT_RANK + 2*D_STATE
#define NBC      32             // BATCH*CH (independent sequences)

// Scan chunking
#define GCH   8                 // chunks per sequence
#define CLEN  (SEQ / GCH)       // 128 timesteps per chunk
#define SUB   32                // x_dbl LDS staging sub-chunk

enum { EPI_NONE = 0, EPI_GATE = 1 };   // EPI_GATE: C = C_old * silu(acc)

__device__ __forceinline__ float siluf(float v) {
    return v / (1.0f + expf(-v));
}

// Fast softplus: hardware v_exp_f32/v_log_f32 via __expf/__logf (~7 VALU ops
// vs ~30 for library expf+log1pf). For v>20, exp may overflow to inf; the
// select discards that side (log(inf)=inf, no NaN). For very negative v,
// __expf->0, __logf(1)=0 exactly. Absolute error vs log1pf(expf(v)) < 1e-6.
__device__ __forceinline__ float softplus_fast(float v) {
    return (v > 20.0f) ? v : __logf(1.0f + __expf(v));
}

// ---------------- bf16-split MFMA GEMM: C[M,N] = A[M,K] * B[N,K]^T --------------
// fp32 inputs are split on the fly into hi+lo bf16 (x = hi + lo, each bf16);
// acc += hi*hi + lo*hi + hi*lo in fp32 AGPRs -> ~2^-17 relative error.
// Block tile 128x128, BK=32, 256 threads = 4 waves, each wave 64x64 via a
// 4x4 grid of 16x16x32 MFMA fragments (48 MFMAs per wave per K-step).
// LDS rows padded to 40 shorts (80 B = 20 banks) to break power-of-2 aliasing.

typedef short short8 __attribute__((ext_vector_type(8)));
typedef float floatx4 __attribute__((ext_vector_type(4)));

__device__ __forceinline__ unsigned short f2bf_rne(float f) {
    unsigned int u = __float_as_uint(f);
    u += 0x7fffu + ((u >> 16) & 1u);
    return (unsigned short)(u >> 16);
}
__device__ __forceinline__ float bf2f(unsigned short h) {
    return __uint_as_float(((unsigned int)h) << 16);
}

template <int EPI>
__global__ __launch_bounds__(256, 2)
void gemm_mfma_split(const float* __restrict__ A, int lda,
                     const float* __restrict__ B, int ldb,
                     float* __restrict__ C, int ldc,
                     int K) {
    __shared__ __align__(16) unsigned short Ah[128][40];
    __shared__ __align__(16) unsigned short Al[128][40];
    __shared__ __align__(16) unsigned short Bh[128][40];
    __shared__ __align__(16) unsigned short Bl[128][40];

    const int tid  = threadIdx.x;
    const int lane = tid & 63;
    const int wv   = tid >> 6;
    const int quad = lane >> 4;
    const int m16  = lane & 15;
    const int wm   = (wv & 1) * 64;       // wave's m-offset in block tile
    const int wn   = (wv >> 1) * 64;      // wave's n-offset
    const int m0   = blockIdx.y * 128;
    const int n0   = blockIdx.x * 128;

    const int srow = tid >> 1;            // staging row 0..127
    const int skb  = (tid & 1) * 16;      // staging k-offset 0 / 16

    floatx4 acc[4][4];
#pragma unroll
    for (int i = 0; i < 4; ++i)
#pragma unroll
        for (int j = 0; j < 4; ++j) acc[i][j] = (floatx4){0.f, 0.f, 0.f, 0.f};

    union U { short8 v; unsigned short u[8]; };

    for (int k0 = 0; k0 < K; k0 += 32) {
        // global loads first (overlap with the barrier)
        const float* ap = A + (size_t)(m0 + srow) * lda + k0 + skb;
        const float* bp = B + (size_t)(n0 + srow) * ldb + k0 + skb;
        const float4 a0 = *(const float4*)(ap + 0);
        const float4 a1 = *(const float4*)(ap + 4);
        const float4 a2 = *(const float4*)(ap + 8);
        const float4 a3 = *(const float4*)(ap + 12);
        const float4 b0 = *(const float4*)(bp + 0);
        const float4 b1 = *(const float4*)(bp + 4);
        const float4 b2 = *(const float4*)(bp + 8);
        const float4 b3 = *(const float4*)(bp + 12);
        const float af[16] = {a0.x, a0.y, a0.z, a0.w, a1.x, a1.y, a1.z, a1.w,
                              a2.x, a2.y, a2.z, a2.w, a3.x, a3.y, a3.z, a3.w};
        const float bf[16] = {b0.x, b0.y, b0.z, b0.w, b1.x, b1.y, b1.z, b1.w,
                              b2.x, b2.y, b2.z, b2.w, b3.x, b3.y, b3.z, b3.w};

        U ah0, ah1, al0, al1, bh0, bh1, bl0, bl1;
#pragma unroll
        for (int e = 0; e < 8; ++e) {
            const unsigned short ha = f2bf_rne(af[e]);
            ah0.u[e] = ha; al0.u[e] = f2bf_rne(af[e] - bf2f(ha));
            const unsigned short hb = f2bf_rne(bf[e]);
            bh0.u[e] = hb; bl0.u[e] = f2bf_rne(bf[e] - bf2f(hb));
        }
#pragma unroll
        for (int e = 0; e < 8; ++e) {
            const unsigned short ha = f2bf_rne(af[8 + e]);
            ah1.u[e] = ha; al1.u[e] = f2bf_rne(af[8 + e] - bf2f(ha));
            const unsigned short hb = f2bf_rne(bf[8 + e]);
            bh1.u[e] = hb; bl1.u[e] = f2bf_rne(bf[8 + e] - bf2f(hb));
        }

        __syncthreads();   // all waves done reading previous tile
        *(short8*)&Ah[srow][skb]     = ah0.v;
        *(short8*)&Ah[srow][skb + 8] = ah1.v;
        *(short8*)&Al[srow][skb]     = al0.v;
        *(short8*)&Al[srow][skb + 8] = al1.v;
        *(short8*)&Bh[srow][skb]     = bh0.v;
        *(short8*)&Bh[srow][skb + 8] = bh1.v;
        *(short8*)&Bl[srow][skb]     = bl0.v;
        *(short8*)&Bl[srow][skb + 8] = bl1.v;
        __syncthreads();

        short8 a_h[4], a_l[4], b_h[4], b_l[4];
#pragma unroll
        for (int i = 0; i < 4; ++i) {
            a_h[i] = *(const short8*)&Ah[wm + i * 16 + m16][quad * 8];
            a_l[i] = *(const short8*)&Al[wm + i * 16 + m16][quad * 8];
            b_h[i] = *(const short8*)&Bh[wn + i * 16 + m16][quad * 8];
            b_l[i] = *(const short8*)&Bl[wn + i * 16 + m16][quad * 8];
        }
#pragma unroll
        for (int i = 0; i < 4; ++i)
#pragma unroll
            for (int j = 0; j < 4; ++j) {
                acc[i][j] = __builtin_amdgcn_mfma_f32_16x16x32_bf16(
                    a_h[i], b_h[j], acc[i][j], 0, 0, 0);
                acc[i][j] = __builtin_amdgcn_mfma_f32_16x16x32_bf16(
                    a_l[i], b_h[j], acc[i][j], 0, 0, 0);
                acc[i][j] = __builtin_amdgcn_mfma_f32_16x16x32_bf16(
                    a_h[i], b_l[j], acc[i][j], 0, 0, 0);
            }
    }

    // Epilogue. C/D layout: col = lane&15, row = quad*4 + reg [m89/m91 verified]
#pragma unroll
    for (int i = 0; i < 4; ++i)
#pragma unroll
        for (int j = 0; j < 4; ++j) {
            const int col = n0 + wn + j * 16 + m16;
#pragma unroll
            for (int r = 0; r < 4; ++r) {
                const int row = m0 + wm + i * 16 + quad * 4 + r;
                const size_t off = (size_t)row * ldc + col;
                const float v = acc[i][j][r];
                if (EPI == EPI_NONE) C[off] = v;
                else                 C[off] = C[off] * siluf(v);
            }
        }
}

// ---------------- fp32 GEMM (kept for the small N=64 x-proj) -------------------
#define TBM 64
#define TBN 64
#define TBK 16

__global__ __launch_bounds__(256)
void gemm_atb(const float* __restrict__ A, int lda,
              const float* __restrict__ B, int ldb,
              float* __restrict__ C, int ldc,
              int K) {
    __shared__ float As[TBM][TBK + 1];
    __shared__ float Bs[TBN][TBK + 1];

    const int tid = threadIdx.x;
    const int tx = tid & 15;
    const int ty = tid >> 4;
    const int m0 = blockIdx.y * TBM;
    const int n0 = blockIdx.x * TBN;

    const int lr = tid >> 2;
    const int lc = (tid & 3) * 4;

    float acc[4][4];
#pragma unroll
    for (int i = 0; i < 4; ++i)
#pragma unroll
        for (int j = 0; j < 4; ++j) acc[i][j] = 0.0f;

    for (int k0 = 0; k0 < K; k0 += TBK) {
        const float4 av = *(const float4*)(A + (size_t)(m0 + lr) * lda + k0 + lc);
        const float4 bv = *(const float4*)(B + (size_t)(n0 + lr) * ldb + k0 + lc);
        As[lr][lc + 0] = av.x; As[lr][lc + 1] = av.y;
        As[lr][lc + 2] = av.z; As[lr][lc + 3] = av.w;
        Bs[lr][lc + 0] = bv.x; Bs[lr][lc + 1] = bv.y;
        Bs[lr][lc + 2] = bv.z; Bs[lr][lc + 3] = bv.w;
        __syncthreads();

#pragma unroll
        for (int kk = 0; kk < TBK; ++kk) {
            float a[4], b[4];
#pragma unroll
            for (int i = 0; i < 4; ++i) a[i] = As[ty * 4 + i][kk];
#pragma unroll
            for (int j = 0; j < 4; ++j) b[j] = Bs[tx * 4 + j][kk];
#pragma unroll
            for (int i = 0; i < 4; ++i)
#pragma unroll
                for (int j = 0; j < 4; ++j) acc[i][j] += a[i] * b[j];
        }
        __syncthreads();
    }

#pragma unroll
    for (int i = 0; i < 4; ++i) {
        const int r = m0 + ty * 4 + i;
#pragma unroll
        for (int j = 0; j < 4; ++j) {
            const int c = n0 + tx * 4 + j;
            C[(size_t)r * ldc + c] = acc[i][j];
        }
    }
}

// ---------------- depthwise causal conv (width 4) + bias + SiLU, IN PLACE ------
__global__ __launch_bounds__(256)
void conv_inplace_silu(float* __restrict__ xs,
                       const float* __restrict__ conv_w,
                       const float* __restrict__ conv_b) {
    const int gid = blockIdx.x * 256 + threadIdx.x;   // 0..NBC*DINNER-1
    const int d = gid & (DINNER - 1);
    const int b = gid >> 10;
    const float w0 = conv_w[d * DCONV + 0];
    const float w1 = conv_w[d * DCONV + 1];
    const float w2 = conv_w[d * DCONV + 2];
    const float w3 = conv_w[d * DCONV + 3];
    const float cb = conv_b[d];
    float x0 = 0.0f, x1 = 0.0f, x2 = 0.0f;
    size_t p = (size_t)b * SEQ * DINNER + d;
    for (int t = 0; t < SEQ; ++t, p += DINNER) {
        const float xv = xs[p];
        const float acc = cb + w0 * x0 + w1 * x1 + w2 * x2 + w3 * xv;
        xs[p] = siluf(acc);
        x0 = x1; x1 = x2; x2 = xv;
    }
}

// ---------------- chunked selective scan (2 passes, write-once scratch) --------
// VALU-bound (98% VALUBusy, 8% HBM): all transcendentals use hardware
// v_exp_f32 / v_log_f32 (__expf/__logf, ~2-3 ulp) instead of OCML library
// calls (~10-30 VALU ops each). PASS0's per-step P[s]*=dA product is replaced
// by dtsum accumulation + one exp(a[s]*dtsum) per chunk (mathematically equal:
// prod_t exp(dt_t*a) == exp(a*sum_t dt_t)).
__device__ __forceinline__ size_t ps_idx(int c, int b, int slot, int d) {
    return ((size_t)(c * NBC + b) * 32 + slot) * DINNER + d;
}

template <int PASS>
__global__ __launch_bounds__(256)
void scan_chunk_kernel(float* __restrict__ xs,        // in: conv'd x; out(P1): y+x*D
                       const float* __restrict__ x_dbl,
                       const float* __restrict__ W_dt,
                       const float* __restrict__ b_dt,
                       const float* __restrict__ A_log,
                       const float* __restrict__ Dp,
                       float* __restrict__ ps) {
    const int tid = threadIdx.x;
    const int c  = blockIdx.x & (GCH - 1);
    const int dg = (blockIdx.x >> 3) & 3;
    const int b  = blockIdx.x >> 5;
    const int d  = (dg << 8) + tid;

    // Chunk GCH-1's (P,S) is never consumed (PASS1 reads only chunks j < c).
    if (PASS == 0 && c == GCH - 1) return;

    float wdt[DTRANK];
#pragma unroll
    for (int k = 0; k < DTRANK; ++k) wdt[k] = W_dt[d * DTRANK + k];
    const float bdt = b_dt[d];
    const float Dv = Dp[d];

    float a[DSTATE], h[DSTATE];
#pragma unroll
    for (int s = 0; s < DSTATE; ++s) a[s] = -expf(A_log[d * DSTATE + s]);

    float dtsum = 0.0f;                    // PASS0: log-domain chunk decay
    if (PASS == 0) {
#pragma unroll
        for (int s = 0; s < DSTATE; ++s) h[s] = 0.0f;
    } else {
        // Fused chunk prefix: h_in = compose(chunks 0..c-1), read-only ps.
#pragma unroll
        for (int s = 0; s < DSTATE; ++s) h[s] = 0.0f;
        for (int j = 0; j < c; ++j) {       // wave-uniform trip count
#pragma unroll
            for (int s = 0; s < DSTATE; ++s) {
                const float Pj = ps[ps_idx(j, b, s, d)];
                const float Sj = ps[ps_idx(j, b, 16 + s, d)];
                h[s] = fmaf(Pj, h[s], Sj);
            }
        }
    }

    __shared__ float bc[SUB][XD];
    const size_t brow = (size_t)b * SEQ + (size_t)c * CLEN;

    for (int t0 = 0; t0 < CLEN; t0 += SUB) {
        __syncthreads();
        for (int e = tid; e < SUB * XD / 4; e += 256) {
            const int tt = e >> 4;
            const int c4 = (e & 15) * 4;
            const float4 v = *(const float4*)(x_dbl + (brow + t0 + tt) * XD + c4);
            bc[tt][c4 + 0] = v.x; bc[tt][c4 + 1] = v.y;
            bc[tt][c4 + 2] = v.z; bc[tt][c4 + 3] = v.w;
        }
        __syncthreads();

        for (int tt = 0; tt < SUB; ++tt) {
            // dt GEMV: 4 independent accumulator chains (break fma latency)
            float g0 = 0.0f, g1 = 0.0f, g2 = 0.0f, g3 = 0.0f;
#pragma unroll
            for (int k = 0; k < DTRANK; k += 4) {
                g0 = fmaf(bc[tt][k + 0], wdt[k + 0], g0);
                g1 = fmaf(bc[tt][k + 1], wdt[k + 1], g1);
                g2 = fmaf(bc[tt][k + 2], wdt[k + 2], g2);
                g3 = fmaf(bc[tt][k + 3], wdt[k + 3], g3);
            }
            const float dtv = softplus_fast(bdt + ((g0 + g1) + (g2 + g3)));
            if (PASS == 0) dtsum += dtv;

            const size_t row = brow + t0 + tt;
            const float xv = xs[row * DINNER + d];
            const float pre = dtv * xv;
            float y0 = 0.0f, y1 = 0.0f;
#pragma unroll
            for (int s = 0; s < DSTATE; ++s) {
                const float dA = __expf(dtv * a[s]);     // v_mul+v_mul+v_exp
                h[s] = fmaf(dA, h[s], pre * bc[tt][DTRANK + s]);
                if (PASS == 1) {
                    if (s & 1) y1 = fmaf(h[s], bc[tt][DTRANK + DSTATE + s], y1);
                    else       y0 = fmaf(h[s], bc[tt][DTRANK + DSTATE + s], y0);
                }
            }
            if (PASS == 1) xs[row * DINNER + d] = fmaf(xv, Dv, y0 + y1);
        }
    }

    if (PASS == 0) {
#pragma unroll
        for (int s = 0; s < DSTATE; ++s) {
            ps[ps_idx(c, b, s, d)]      = __expf(a[s] * dtsum);
            ps[ps_idx(c, b, 16 + s, d)] = h[s];
        }
    }
}

// ---------------- launch ----------------
// Workspace: NROWS*DINNER floats = 128 MiB (xs -> conv'd -> y, in place).
// d_out doubles as scratch before the final GEMM: x_dbl (8 MiB) + PS (32 MiB).
// No memset needed: x_dbl fully written by gemm_atb before scan reads it;
// ps chunks 0..GCH-2 fully written by PASS0 before PASS1 reads them; out
// fully written by the final GEMM.
extern "C" void kernel_launch(void* const* d_in, const int* in_sizes, int n_in,
                              void* d_out, int out_size, void* d_ws, size_t ws_size,
                              hipStream_t stream) {
    const float* x       = (const float*)d_in[0];
    const float* W_in    = (const float*)d_in[1];
    const float* conv_w  = (const float*)d_in[2];
    const float* conv_b  = (const float*)d_in[3];
    const float* W_xproj = (const float*)d_in[4];
    const float* W_dt    = (const float*)d_in[5];
    const float* b_dt    = (const float*)d_in[6];
    const float* A_log   = (const float*)d_in[7];
    const float* Dp      = (const float*)d_in[8];
    const float* W_out   = (const float*)d_in[9];
    float* out = (float*)d_out;

    float* xs    = (float*)d_ws;             // BIG floats, in-place pipeline
    float* x_dbl = out;                      // d_out[0 .. 2M)
    float* ps    = out + (size_t)NROWS * XD; // d_out[2M .. 10.5M) of 16.7M

    dim3 blk(256);

    // 1. xs = u @ W_in[0:1024]^T   (M=32768, N=1024, K=512)  [MFMA bf16-split]
    gemm_mfma_split<EPI_NONE><<<dim3(DINNER / 128, NROWS / 128), blk, 0, stream>>>(
        x, DMODEL, W_in, DMODEL, xs, DINNER, DMODEL);

    // 2. depthwise conv + bias + SiLU, in place over xs
    conv_inplace_silu<<<NBC * DINNER / 256, blk, 0, stream>>>(xs, conv_w, conv_b);

    // 3. x_dbl = xs @ W_xproj^T    (M=32768, N=64, K=1024) -> stashed in d_out
    gemm_atb<<<dim3(XD / TBN, NROWS / TBM), blk, 0, stream>>>(
        xs, DINNER, W_xproj, DINNER, x_dbl, XD, DINNER);

    // 4a. chunk-local (P, S) -> ps (write-once; chunk GCH-1 early-exits)
    scan_chunk_kernel<0><<<NBC * 4 * GCH, blk, 0, stream>>>(
        xs, x_dbl, W_dt, b_dt, A_log, Dp, ps);
    // 4b. fused prefix + re-walk chunks, write ungated y + x*D over xs
    scan_chunk_kernel<1><<<NBC * 4 * GCH, blk, 0, stream>>>(
        xs, x_dbl, W_dt, b_dt, A_log, Dp, ps);

    // 5. z-gate: z = u @ W_in[1024:2048]^T, xs *= silu(z)  [MFMA bf16-split]
    gemm_mfma_split<EPI_GATE><<<dim3(DINNER / 128, NROWS / 128), blk, 0, stream>>>(
        x, DMODEL, W_in + (size_t)DINNER * DMODEL, DMODEL, xs, DINNER, DMODEL);

    // 6. out = y @ W_out^T         (M=32768, N=512, K=1024)  [MFMA bf16-split]
    gemm_mfma_split<EPI_NONE><<<dim3(DMODEL / 128, NROWS / 128), blk, 0, stream>>>(
        xs, DINNER, W_out, DINNER, out, DMODEL, DINNER);
}

// Round 3
// 1094.962 us; speedup vs baseline: 1.4423x; 1.0729x over previous
//
#include <hip/hip_runtime.h>
#include <hip/hip_bf16.h>
#include <math.h>

// Problem dims (fixed)
#define BATCHN   4
#define CHN      8
#define SEQ      1024
#define DMODEL   512
#define DSTATE   16
#define DCONV    4
#define DINNER   1024
#define DTRANK   32
#define NROWS    32768          // BATCH*CH*SEQ
#define XD       64             // DT_RANK + 2*D_STATE
#define NBC      32             // BATCH*CH (independent sequences)

// Scan chunking
#define GCH   8                 // chunks per sequence
#define CLEN  (SEQ / GCH)       // 128 timesteps per chunk
#define SUB   32                // x_dbl LDS staging sub-chunk

enum { EPI_NONE = 0, EPI_GATE = 1 };   // EPI_GATE: C = C_old * silu(acc)

__device__ __forceinline__ float siluf(float v) {
    return v / (1.0f + expf(-v));
}
__device__ __forceinline__ float softplus_fast(float v) {
    return (v > 20.0f) ? v : __logf(1.0f + __expf(v));
}

typedef short short8 __attribute__((ext_vector_type(8)));
typedef float floatx4 __attribute__((ext_vector_type(4)));

__device__ __forceinline__ unsigned short f2bf_rne(float f) {
    unsigned int u = __float_as_uint(f);
    u += 0x7fffu + ((u >> 16) & 1u);
    return (unsigned short)(u >> 16);
}
__device__ __forceinline__ float bf2f(unsigned short h) {
    return __uint_as_float(((unsigned int)h) << 16);
}

// ---------------- prepass: f32 [R][K] -> blocked split bf16 --------------------
// Per (row, kblock of 32 k's): 128 B = [32 x hi bf16 | 32 x lo bf16], linear.
// hi+lo pairs are bit-identical to the GEMM's on-the-fly split (same f2bf_rne).
__global__ __launch_bounds__(256)
void split_w(const float* __restrict__ W, unsigned char* __restrict__ W2,
             int R, int K) {
    const int KB = K >> 5;
    const int idx = blockIdx.x * 256 + threadIdx.x;   // one per (row, kblock)
    if (idx >= R * KB) return;
    const int row = idx / KB;
    const int kb  = idx - row * KB;
    const float* src = W + (size_t)row * K + kb * 32;
    unsigned short h[32], l[32];
#pragma unroll
    for (int e = 0; e < 32; e += 4) {
        const float4 v = *(const float4*)(src + e);
        const float vv[4] = {v.x, v.y, v.z, v.w};
#pragma unroll
        for (int q = 0; q < 4; ++q) {
            const unsigned short hi = f2bf_rne(vv[q]);
            h[e + q] = hi;
            l[e + q] = f2bf_rne(vv[q] - bf2f(hi));
        }
    }
    unsigned char* dst = W2 + ((size_t)row * KB + kb) * 128;
    union { short8 v; unsigned short u[8]; } pk;
#pragma unroll
    for (int c = 0; c < 4; ++c) {           // hi bytes [0,64)
#pragma unroll
        for (int e = 0; e < 8; ++e) pk.u[e] = h[c * 8 + e];
        *(short8*)(dst + c * 16) = pk.v;
    }
#pragma unroll
    for (int c = 0; c < 4; ++c) {           // lo bytes [64,128)
#pragma unroll
        for (int e = 0; e < 8; ++e) pk.u[e] = l[c * 8 + e];
        *(short8*)(dst + 64 + c * 16) = pk.v;
    }
}

// ---------------- bf16-split MFMA GEMM: C[M,N] = A[M,K] * B[N,K]^T --------------
// fp32 A is split on the fly into hi+lo bf16 (x = hi + lo, each bf16);
// acc += hi*hi + lo*hi + hi*lo in fp32 AGPRs -> ~2^-17 relative error.
// B_PRE: B operand comes pre-split (prepass above) -> staging is pure
// short8 load + LDS store, ZERO conversion VALU (the round-1 kernel spent
// ~145 VALU ops/thread/K-step re-splitting the same weights in every block).
// Block tile 128x128, BK=32, 256 threads = 4 waves, each wave 64x64 via a
// 4x4 grid of 16x16x32 MFMA fragments (48 MFMAs per wave per K-step).
// LDS rows padded to 40 shorts (80 B = 20 banks) to break power-of-2 aliasing.
template <bool B_PRE, int EPI>
__global__ __launch_bounds__(256, 2)
void gemm_split(const float* __restrict__ A, int lda,
                const float* __restrict__ Bf, const unsigned char* __restrict__ B2,
                int ldb,
                float* __restrict__ C, int ldc,
                int K) {
    __shared__ __align__(16) unsigned short Ah[128][40];
    __shared__ __align__(16) unsigned short Al[128][40];
    __shared__ __align__(16) unsigned short Bh[128][40];
    __shared__ __align__(16) unsigned short Bl[128][40];

    const int tid  = threadIdx.x;
    const int lane = tid & 63;
    const int wv   = tid >> 6;
    const int quad = lane >> 4;
    const int m16  = lane & 15;
    const int wm   = (wv & 1) * 64;       // wave's m-offset in block tile
    const int wn   = (wv >> 1) * 64;      // wave's n-offset
    const int m0   = blockIdx.y * 128;
    const int n0   = blockIdx.x * 128;

    const int srow = tid >> 1;            // staging row 0..127
    const int skb  = (tid & 1) * 16;      // staging k-offset 0 / 16

    const unsigned char* bptr = nullptr;
    if constexpr (B_PRE)
        bptr = B2 + (size_t)(n0 + srow) * (K >> 5) * 128 + 2 * skb;

    floatx4 acc[4][4];
#pragma unroll
    for (int i = 0; i < 4; ++i)
#pragma unroll
        for (int j = 0; j < 4; ++j) acc[i][j] = (floatx4){0.f, 0.f, 0.f, 0.f};

    union U { short8 v; unsigned short u[8]; };

    for (int k0 = 0; k0 < K; k0 += 32) {
        // global loads first (overlap with the barrier)
        const float* ap = A + (size_t)(m0 + srow) * lda + k0 + skb;
        const float4 a0 = *(const float4*)(ap + 0);
        const float4 a1 = *(const float4*)(ap + 4);
        const float4 a2 = *(const float4*)(ap + 8);
        const float4 a3 = *(const float4*)(ap + 12);
        const float af[16] = {a0.x, a0.y, a0.z, a0.w, a1.x, a1.y, a1.z, a1.w,
                              a2.x, a2.y, a2.z, a2.w, a3.x, a3.y, a3.z, a3.w};

        short8 pb0, pb1, pb2, pb3;         // B_PRE path: raw pre-split data
        U bh0, bh1, bl0, bl1;              // !B_PRE path: on-the-fly split
        if constexpr (B_PRE) {
            pb0 = *(const short8*)(bptr);        // hi, k [skb, skb+8)
            pb1 = *(const short8*)(bptr + 16);   // hi, k [skb+8, skb+16)
            pb2 = *(const short8*)(bptr + 64);   // lo, k [skb, skb+8)
            pb3 = *(const short8*)(bptr + 80);   // lo, k [skb+8, skb+16)
            bptr += 128;
        } else {
            const float* bp = Bf + (size_t)(n0 + srow) * ldb + k0 + skb;
            const float4 b0 = *(const float4*)(bp + 0);
            const float4 b1 = *(const float4*)(bp + 4);
            const float4 b2 = *(const float4*)(bp + 8);
            const float4 b3 = *(const float4*)(bp + 12);
            const float bf[16] = {b0.x, b0.y, b0.z, b0.w, b1.x, b1.y, b1.z, b1.w,
                                  b2.x, b2.y, b2.z, b2.w, b3.x, b3.y, b3.z, b3.w};
#pragma unroll
            for (int e = 0; e < 8; ++e) {
                const unsigned short ha = f2bf_rne(bf[e]);
                bh0.u[e] = ha; bl0.u[e] = f2bf_rne(bf[e] - bf2f(ha));
                const unsigned short hb = f2bf_rne(bf[8 + e]);
                bh1.u[e] = hb; bl1.u[e] = f2bf_rne(bf[8 + e] - bf2f(hb));
            }
        }

        U ah0, ah1, al0, al1;
#pragma unroll
        for (int e = 0; e < 8; ++e) {
            const unsigned short ha = f2bf_rne(af[e]);
            ah0.u[e] = ha; al0.u[e] = f2bf_rne(af[e] - bf2f(ha));
            const unsigned short hb = f2bf_rne(af[8 + e]);
            ah1.u[e] = hb; al1.u[e] = f2bf_rne(af[8 + e] - bf2f(hb));
        }

        __syncthreads();   // all waves done reading previous tile
        *(short8*)&Ah[srow][skb]     = ah0.v;
        *(short8*)&Ah[srow][skb + 8] = ah1.v;
        *(short8*)&Al[srow][skb]     = al0.v;
        *(short8*)&Al[srow][skb + 8] = al1.v;
        if constexpr (B_PRE) {
            *(short8*)&Bh[srow][skb]     = pb0;
            *(short8*)&Bh[srow][skb + 8] = pb1;
            *(short8*)&Bl[srow][skb]     = pb2;
            *(short8*)&Bl[srow][skb + 8] = pb3;
        } else {
            *(short8*)&Bh[srow][skb]     = bh0.v;
            *(short8*)&Bh[srow][skb + 8] = bh1.v;
            *(short8*)&Bl[srow][skb]     = bl0.v;
            *(short8*)&Bl[srow][skb + 8] = bl1.v;
        }
        __syncthreads();

        short8 a_h[4], a_l[4], b_h[4], b_l[4];
#pragma unroll
        for (int i = 0; i < 4; ++i) {
            a_h[i] = *(const short8*)&Ah[wm + i * 16 + m16][quad * 8];
            a_l[i] = *(const short8*)&Al[wm + i * 16 + m16][quad * 8];
            b_h[i] = *(const short8*)&Bh[wn + i * 16 + m16][quad * 8];
            b_l[i] = *(const short8*)&Bl[wn + i * 16 + m16][quad * 8];
        }
#pragma unroll
        for (int i = 0; i < 4; ++i)
#pragma unroll
            for (int j = 0; j < 4; ++j) {
                acc[i][j] = __builtin_amdgcn_mfma_f32_16x16x32_bf16(
                    a_h[i], b_h[j], acc[i][j], 0, 0, 0);
                acc[i][j] = __builtin_amdgcn_mfma_f32_16x16x32_bf16(
                    a_l[i], b_h[j], acc[i][j], 0, 0, 0);
                acc[i][j] = __builtin_amdgcn_mfma_f32_16x16x32_bf16(
                    a_h[i], b_l[j], acc[i][j], 0, 0, 0);
            }
    }

    // Epilogue. C/D layout: col = lane&15, row = quad*4 + reg [m89/m91 verified]
#pragma unroll
    for (int i = 0; i < 4; ++i)
#pragma unroll
        for (int j = 0; j < 4; ++j) {
            const int col = n0 + wn + j * 16 + m16;
#pragma unroll
            for (int r = 0; r < 4; ++r) {
                const int row = m0 + wm + i * 16 + quad * 4 + r;
                const size_t off = (size_t)row * ldc + col;
                const float v = acc[i][j][r];
                if (EPI == EPI_NONE) C[off] = v;
                else                 C[off] = C[off] * siluf(v);
            }
        }
}

// ---------------- fp32 GEMM (kept for the small N=64 x-proj) -------------------
#define TBM 64
#define TBN 64
#define TBK 16

__global__ __launch_bounds__(256)
void gemm_atb(const float* __restrict__ A, int lda,
              const float* __restrict__ B, int ldb,
              float* __restrict__ C, int ldc,
              int K) {
    __shared__ float As[TBM][TBK + 1];
    __shared__ float Bs[TBN][TBK + 1];

    const int tid = threadIdx.x;
    const int tx = tid & 15;
    const int ty = tid >> 4;
    const int m0 = blockIdx.y * TBM;
    const int n0 = blockIdx.x * TBN;

    const int lr = tid >> 2;
    const int lc = (tid & 3) * 4;

    float acc[4][4];
#pragma unroll
    for (int i = 0; i < 4; ++i)
#pragma unroll
        for (int j = 0; j < 4; ++j) acc[i][j] = 0.0f;

    for (int k0 = 0; k0 < K; k0 += TBK) {
        const float4 av = *(const float4*)(A + (size_t)(m0 + lr) * lda + k0 + lc);
        const float4 bv = *(const float4*)(B + (size_t)(n0 + lr) * ldb + k0 + lc);
        As[lr][lc + 0] = av.x; As[lr][lc + 1] = av.y;
        As[lr][lc + 2] = av.z; As[lr][lc + 3] = av.w;
        Bs[lr][lc + 0] = bv.x; Bs[lr][lc + 1] = bv.y;
        Bs[lr][lc + 2] = bv.z; Bs[lr][lc + 3] = bv.w;
        __syncthreads();

#pragma unroll
        for (int kk = 0; kk < TBK; ++kk) {
            float a[4], b[4];
#pragma unroll
            for (int i = 0; i < 4; ++i) a[i] = As[ty * 4 + i][kk];
#pragma unroll
            for (int j = 0; j < 4; ++j) b[j] = Bs[tx * 4 + j][kk];
#pragma unroll
            for (int i = 0; i < 4; ++i)
#pragma unroll
                for (int j = 0; j < 4; ++j) acc[i][j] += a[i] * b[j];
        }
        __syncthreads();
    }

#pragma unroll
    for (int i = 0; i < 4; ++i) {
        const int r = m0 + ty * 4 + i;
#pragma unroll
        for (int j = 0; j < 4; ++j) {
            const int c = n0 + tx * 4 + j;
            C[(size_t)r * ldc + c] = acc[i][j];
        }
    }
}

// ---------------- depthwise causal conv (width 4) + bias + SiLU, IN PLACE ------
__global__ __launch_bounds__(256)
void conv_inplace_silu(float* __restrict__ xs,
                       const float* __restrict__ conv_w,
                       const float* __restrict__ conv_b) {
    const int gid = blockIdx.x * 256 + threadIdx.x;   // 0..NBC*DINNER-1
    const int d = gid & (DINNER - 1);
    const int b = gid >> 10;
    const float w0 = conv_w[d * DCONV + 0];
    const float w1 = conv_w[d * DCONV + 1];
    const float w2 = conv_w[d * DCONV + 2];
    const float w3 = conv_w[d * DCONV + 3];
    const float cb = conv_b[d];
    float x0 = 0.0f, x1 = 0.0f, x2 = 0.0f;
    size_t p = (size_t)b * SEQ * DINNER + d;
    for (int t = 0; t < SEQ; ++t, p += DINNER) {
        const float xv = xs[p];
        const float acc = cb + w0 * x0 + w1 * x1 + w2 * x2 + w3 * xv;
        xs[p] = siluf(acc);
        x0 = x1; x1 = x2; x2 = xv;
    }
}

// ---------------- chunked selective scan (2 passes, write-once scratch) --------
__device__ __forceinline__ size_t ps_idx(int c, int b, int slot, int d) {
    return ((size_t)(c * NBC + b) * 32 + slot) * DINNER + d;
}

template <int PASS>
__global__ __launch_bounds__(256)
void scan_chunk_kernel(float* __restrict__ xs,        // in: conv'd x; out(P1): y+x*D
                       const float* __restrict__ x_dbl,
                       const float* __restrict__ W_dt,
                       const float* __restrict__ b_dt,
                       const float* __restrict__ A_log,
                       const float* __restrict__ Dp,
                       float* __restrict__ ps) {
    const int tid = threadIdx.x;
    const int c  = blockIdx.x & (GCH - 1);
    const int dg = (blockIdx.x >> 3) & 3;
    const int b  = blockIdx.x >> 5;
    const int d  = (dg << 8) + tid;

    // Chunk GCH-1's (P,S) is never consumed (PASS1 reads only chunks j < c).
    if (PASS == 0 && c == GCH - 1) return;

    float wdt[DTRANK];
#pragma unroll
    for (int k = 0; k < DTRANK; ++k) wdt[k] = W_dt[d * DTRANK + k];
    const float bdt = b_dt[d];
    const float Dv = Dp[d];

    float a[DSTATE], h[DSTATE];
#pragma unroll
    for (int s = 0; s < DSTATE; ++s) a[s] = -expf(A_log[d * DSTATE + s]);

    float dtsum = 0.0f;                    // PASS0: log-domain chunk decay
    if (PASS == 0) {
#pragma unroll
        for (int s = 0; s < DSTATE; ++s) h[s] = 0.0f;
    } else {
        // Fused chunk prefix: h_in = compose(chunks 0..c-1), read-only ps.
#pragma unroll
        for (int s = 0; s < DSTATE; ++s) h[s] = 0.0f;
        for (int j = 0; j < c; ++j) {       // wave-uniform trip count
#pragma unroll
            for (int s = 0; s < DSTATE; ++s) {
                const float Pj = ps[ps_idx(j, b, s, d)];
                const float Sj = ps[ps_idx(j, b, 16 + s, d)];
                h[s] = fmaf(Pj, h[s], Sj);
            }
        }
    }

    __shared__ float bc[SUB][XD];
    const size_t brow = (size_t)b * SEQ + (size_t)c * CLEN;

    for (int t0 = 0; t0 < CLEN; t0 += SUB) {
        __syncthreads();
        for (int e = tid; e < SUB * XD / 4; e += 256) {
            const int tt = e >> 4;
            const int c4 = (e & 15) * 4;
            const float4 v = *(const float4*)(x_dbl + (brow + t0 + tt) * XD + c4);
            bc[tt][c4 + 0] = v.x; bc[tt][c4 + 1] = v.y;
            bc[tt][c4 + 2] = v.z; bc[tt][c4 + 3] = v.w;
        }
        __syncthreads();

        for (int tt = 0; tt < SUB; ++tt) {
            // dt GEMV: 4 independent accumulator chains (break fma latency)
            float g0 = 0.0f, g1 = 0.0f, g2 = 0.0f, g3 = 0.0f;
#pragma unroll
            for (int k = 0; k < DTRANK; k += 4) {
                g0 = fmaf(bc[tt][k + 0], wdt[k + 0], g0);
                g1 = fmaf(bc[tt][k + 1], wdt[k + 1], g1);
                g2 = fmaf(bc[tt][k + 2], wdt[k + 2], g2);
                g3 = fmaf(bc[tt][k + 3], wdt[k + 3], g3);
            }
            const float dtv = softplus_fast(bdt + ((g0 + g1) + (g2 + g3)));
            if (PASS == 0) dtsum += dtv;

            const size_t row = brow + t0 + tt;
            const float xv = xs[row * DINNER + d];
            const float pre = dtv * xv;
            float y0 = 0.0f, y1 = 0.0f;
#pragma unroll
            for (int s = 0; s < DSTATE; ++s) {
                const float dA = __expf(dtv * a[s]);     // v_mul+v_mul+v_exp
                h[s] = fmaf(dA, h[s], pre * bc[tt][DTRANK + s]);
                if (PASS == 1) {
                    if (s & 1) y1 = fmaf(h[s], bc[tt][DTRANK + DSTATE + s], y1);
                    else       y0 = fmaf(h[s], bc[tt][DTRANK + DSTATE + s], y0);
                }
            }
            if (PASS == 1) xs[row * DINNER + d] = fmaf(xv, Dv, y0 + y1);
        }
    }

    if (PASS == 0) {
#pragma unroll
        for (int s = 0; s < DSTATE; ++s) {
            ps[ps_idx(c, b, s, d)]      = __expf(a[s] * dtsum);
            ps[ps_idx(c, b, 16 + s, d)] = h[s];
        }
    }
}

// ---------------- launch ----------------
// Workspace ws: xs = NROWS*DINNER floats = 128 MiB (x -> conv'd -> y, in place);
// optional +2 MiB tail for pre-split W_out (checked against ws_size at launch).
// d_out doubles as scratch before the final GEMM:
//   [ 0,  8 MB)  x_dbl   (dead before step 6)
//   [ 8, 40 MB)  ps      (dead before step 6)
//   [40, 44 MB)  W2in    (dead before step 6 -- step 6 never reads d_out)
// Step 6 overwrites all of d_out; everything it reads lives in ws / d_in.
// Every scratch region is fully rewritten each launch (graph-replay safe).
extern "C" void kernel_launch(void* const* d_in, const int* in_sizes, int n_in,
                              void* d_out, int out_size, void* d_ws, size_t ws_size,
                              hipStream_t stream) {
    const float* x       = (const float*)d_in[0];
    const float* W_in    = (const float*)d_in[1];
    const float* conv_w  = (const float*)d_in[2];
    const float* conv_b  = (const float*)d_in[3];
    const float* W_xproj = (const float*)d_in[4];
    const float* W_dt    = (const float*)d_in[5];
    const float* b_dt    = (const float*)d_in[6];
    const float* A_log   = (const float*)d_in[7];
    const float* Dp      = (const float*)d_in[8];
    const float* W_out   = (const float*)d_in[9];
    float* out = (float*)d_out;

    float* xs    = (float*)d_ws;             // in-place pipeline buffer
    float* x_dbl = out;                      // d_out[0 .. 2M floats)
    float* ps    = out + (size_t)NROWS * XD; // d_out[2M .. 10.5M floats)
    unsigned char* w2in = (unsigned char*)(out + 10485760);  // 4 MiB split W_in

    const size_t xs_bytes = (size_t)NROWS * DINNER * 4;      // 128 MiB
    unsigned char* w2out = (unsigned char*)d_ws + xs_bytes;  // 2 MiB split W_out
    const bool have_wout = ws_size >= xs_bytes + (size_t)DMODEL * (DINNER / 32) * 128;

    dim3 blk(256);

    // 0. prepass: split weights -> blocked bf16 hi/lo (tiny; ~6 MiB traffic)
    split_w<<<(2048 * 16) / 256, blk, 0, stream>>>(W_in, w2in, 2048, DMODEL);
    if (have_wout)
        split_w<<<(512 * 32) / 256, blk, 0, stream>>>(W_out, w2out, DMODEL, DINNER);

    // 1. xs = u @ W_in[0:1024]^T   (M=32768, N=1024, K=512)  [B pre-split]
    gemm_split<true, EPI_NONE><<<dim3(DINNER / 128, NROWS / 128), blk, 0, stream>>>(
        x, DMODEL, nullptr, w2in, 0, xs, DINNER, DMODEL);

    // 2. depthwise conv + bias + SiLU, in place over xs
    conv_inplace_silu<<<NBC * DINNER / 256, blk, 0, stream>>>(xs, conv_w, conv_b);

    // 3. x_dbl = xs @ W_xproj^T    (M=32768, N=64, K=1024) -> stashed in d_out
    gemm_atb<<<dim3(XD / TBN, NROWS / TBM), blk, 0, stream>>>(
        xs, DINNER, W_xproj, DINNER, x_dbl, XD, DINNER);

    // 4a. chunk-local (P, S) -> ps (write-once; chunk GCH-1 early-exits)
    scan_chunk_kernel<0><<<NBC * 4 * GCH, blk, 0, stream>>>(
        xs, x_dbl, W_dt, b_dt, A_log, Dp, ps);
    // 4b. fused prefix + re-walk chunks, write ungated y + x*D over xs
    scan_chunk_kernel<1><<<NBC * 4 * GCH, blk, 0, stream>>>(
        xs, x_dbl, W_dt, b_dt, A_log, Dp, ps);

    // 5. z-gate: z = u @ W_in[1024:2048]^T, xs *= silu(z)  [B pre-split]
    gemm_split<true, EPI_GATE><<<dim3(DINNER / 128, NROWS / 128), blk, 0, stream>>>(
        x, DMODEL, nullptr, w2in + (size_t)1024 * 16 * 128, 0, xs, DINNER, DMODEL);

    // 6. out = y @ W_out^T         (M=32768, N=512, K=1024)
    if (have_wout)
        gemm_split<true, EPI_NONE><<<dim3(DMODEL / 128, NROWS / 128), blk, 0, stream>>>(
            xs, DINNER, nullptr, w2out, 0, out, DMODEL, DINNER);
    else
        gemm_split<false, EPI_NONE><<<dim3(DMODEL / 128, NROWS / 128), blk, 0, stream>>>(
            xs, DINNER, W_out, nullptr, DINNER, out, DMODEL, DINNER);
}

// Round 4
// 971.890 us; speedup vs baseline: 1.6249x; 1.1266x over previous
//
#include <hip/hip_runtime.h>
#include <hip/hip_bf16.h>
#include <math.h>

// Problem dims (fixed)
#define BATCHN   4
#define CHN      8
#define SEQ      1024
#define DMODEL   512
#define DSTATE   16
#define DCONV    4
#define DINNER   1024
#define DTRANK   32
#define NROWS    32768          // BATCH*CH*SEQ
#define XD       64             // DT_RANK + 2*D_STATE
#define NBC      32             // BATCH*CH (independent sequences)

// Scan chunking
#define GCH   16                // chunks per sequence
#define CLEN  (SEQ / GCH)       // 64 timesteps per chunk
#define SUB   32                // x_dbl LDS staging sub-chunk
#define PSLOT 17                // ps slots per (chunk,b,d): [dtsum | S x16]

// Conv splitting
#define CSPL  8                 // t-splits per sequence
#define CTS   (SEQ / CSPL)      // 128 timesteps per split

enum { EPI_NONE = 0, EPI_GATE = 1 };   // EPI_GATE: C = C_old * silu(acc)

__device__ __forceinline__ float siluf(float v) {
    return v / (1.0f + expf(-v));
}
__device__ __forceinline__ float softplus_fast(float v) {
    return (v > 20.0f) ? v : __logf(1.0f + __expf(v));
}

typedef short short8 __attribute__((ext_vector_type(8)));
typedef float floatx4 __attribute__((ext_vector_type(4)));

__device__ __forceinline__ unsigned short f2bf_rne(float f) {
    unsigned int u = __float_as_uint(f);
    u += 0x7fffu + ((u >> 16) & 1u);
    return (unsigned short)(u >> 16);
}
__device__ __forceinline__ float bf2f(unsigned short h) {
    return __uint_as_float(((unsigned int)h) << 16);
}

// ---------------- prepass: f32 [R][K] -> blocked split bf16 --------------------
// Per (row, kblock of 32 k's): 128 B = [32 x hi bf16 | 32 x lo bf16], linear.
// hi+lo pairs are bit-identical to the GEMM's on-the-fly split (same f2bf_rne).
__global__ __launch_bounds__(256)
void split_w(const float* __restrict__ W, unsigned char* __restrict__ W2,
             int R, int K) {
    const int KB = K >> 5;
    const int idx = blockIdx.x * 256 + threadIdx.x;   // one per (row, kblock)
    if (idx >= R * KB) return;
    const int row = idx / KB;
    const int kb  = idx - row * KB;
    const float* src = W + (size_t)row * K + kb * 32;
    unsigned short h[32], l[32];
#pragma unroll
    for (int e = 0; e < 32; e += 4) {
        const float4 v = *(const float4*)(src + e);
        const float vv[4] = {v.x, v.y, v.z, v.w};
#pragma unroll
        for (int q = 0; q < 4; ++q) {
            const unsigned short hi = f2bf_rne(vv[q]);
            h[e + q] = hi;
            l[e + q] = f2bf_rne(vv[q] - bf2f(hi));
        }
    }
    unsigned char* dst = W2 + ((size_t)row * KB + kb) * 128;
    union { short8 v; unsigned short u[8]; } pk;
#pragma unroll
    for (int c = 0; c < 4; ++c) {           // hi bytes [0,64)
#pragma unroll
        for (int e = 0; e < 8; ++e) pk.u[e] = h[c * 8 + e];
        *(short8*)(dst + c * 16) = pk.v;
    }
#pragma unroll
    for (int c = 0; c < 4; ++c) {           // lo bytes [64,128)
#pragma unroll
        for (int e = 0; e < 8; ++e) pk.u[e] = l[c * 8 + e];
        *(short8*)(dst + 64 + c * 16) = pk.v;
    }
}

// ---------------- bf16-split MFMA GEMM: C[M,N] = A[M,K] * B[N,K]^T --------------
// (unchanged from round 3 -- known good)
template <bool B_PRE, int EPI>
__global__ __launch_bounds__(256, 2)
void gemm_split(const float* __restrict__ A, int lda,
                const float* __restrict__ Bf, const unsigned char* __restrict__ B2,
                int ldb,
                float* __restrict__ C, int ldc,
                int K) {
    __shared__ __align__(16) unsigned short Ah[128][40];
    __shared__ __align__(16) unsigned short Al[128][40];
    __shared__ __align__(16) unsigned short Bh[128][40];
    __shared__ __align__(16) unsigned short Bl[128][40];

    const int tid  = threadIdx.x;
    const int lane = tid & 63;
    const int wv   = tid >> 6;
    const int quad = lane >> 4;
    const int m16  = lane & 15;
    const int wm   = (wv & 1) * 64;       // wave's m-offset in block tile
    const int wn   = (wv >> 1) * 64;      // wave's n-offset
    const int m0   = blockIdx.y * 128;
    const int n0   = blockIdx.x * 128;

    const int srow = tid >> 1;            // staging row 0..127
    const int skb  = (tid & 1) * 16;      // staging k-offset 0 / 16

    const unsigned char* bptr = nullptr;
    if constexpr (B_PRE)
        bptr = B2 + (size_t)(n0 + srow) * (K >> 5) * 128 + 2 * skb;

    floatx4 acc[4][4];
#pragma unroll
    for (int i = 0; i < 4; ++i)
#pragma unroll
        for (int j = 0; j < 4; ++j) acc[i][j] = (floatx4){0.f, 0.f, 0.f, 0.f};

    union U { short8 v; unsigned short u[8]; };

    for (int k0 = 0; k0 < K; k0 += 32) {
        // global loads first (overlap with the barrier)
        const float* ap = A + (size_t)(m0 + srow) * lda + k0 + skb;
        const float4 a0 = *(const float4*)(ap + 0);
        const float4 a1 = *(const float4*)(ap + 4);
        const float4 a2 = *(const float4*)(ap + 8);
        const float4 a3 = *(const float4*)(ap + 12);
        const float af[16] = {a0.x, a0.y, a0.z, a0.w, a1.x, a1.y, a1.z, a1.w,
                              a2.x, a2.y, a2.z, a2.w, a3.x, a3.y, a3.z, a3.w};

        short8 pb0, pb1, pb2, pb3;         // B_PRE path: raw pre-split data
        U bh0, bh1, bl0, bl1;              // !B_PRE path: on-the-fly split
        if constexpr (B_PRE) {
            pb0 = *(const short8*)(bptr);        // hi, k [skb, skb+8)
            pb1 = *(const short8*)(bptr + 16);   // hi, k [skb+8, skb+16)
            pb2 = *(const short8*)(bptr + 64);   // lo, k [skb, skb+8)
            pb3 = *(const short8*)(bptr + 80);   // lo, k [skb+8, skb+16)
            bptr += 128;
        } else {
            const float* bp = Bf + (size_t)(n0 + srow) * ldb + k0 + skb;
            const float4 b0 = *(const float4*)(bp + 0);
            const float4 b1 = *(const float4*)(bp + 4);
            const float4 b2 = *(const float4*)(bp + 8);
            const float4 b3 = *(const float4*)(bp + 12);
            const float bf[16] = {b0.x, b0.y, b0.z, b0.w, b1.x, b1.y, b1.z, b1.w,
                                  b2.x, b2.y, b2.z, b2.w, b3.x, b3.y, b3.z, b3.w};
#pragma unroll
            for (int e = 0; e < 8; ++e) {
                const unsigned short ha = f2bf_rne(bf[e]);
                bh0.u[e] = ha; bl0.u[e] = f2bf_rne(bf[e] - bf2f(ha));
                const unsigned short hb = f2bf_rne(bf[8 + e]);
                bh1.u[e] = hb; bl1.u[e] = f2bf_rne(bf[8 + e] - bf2f(hb));
            }
        }

        U ah0, ah1, al0, al1;
#pragma unroll
        for (int e = 0; e < 8; ++e) {
            const unsigned short ha = f2bf_rne(af[e]);
            ah0.u[e] = ha; al0.u[e] = f2bf_rne(af[e] - bf2f(ha));
            const unsigned short hb = f2bf_rne(af[8 + e]);
            ah1.u[e] = hb; al1.u[e] = f2bf_rne(af[8 + e] - bf2f(hb));
        }

        __syncthreads();   // all waves done reading previous tile
        *(short8*)&Ah[srow][skb]     = ah0.v;
        *(short8*)&Ah[srow][skb + 8] = ah1.v;
        *(short8*)&Al[srow][skb]     = al0.v;
        *(short8*)&Al[srow][skb + 8] = al1.v;
        if constexpr (B_PRE) {
            *(short8*)&Bh[srow][skb]     = pb0;
            *(short8*)&Bh[srow][skb + 8] = pb1;
            *(short8*)&Bl[srow][skb]     = pb2;
            *(short8*)&Bl[srow][skb + 8] = pb3;
        } else {
            *(short8*)&Bh[srow][skb]     = bh0.v;
            *(short8*)&Bh[srow][skb + 8] = bh1.v;
            *(short8*)&Bl[srow][skb]     = bl0.v;
            *(short8*)&Bl[srow][skb + 8] = bl1.v;
        }
        __syncthreads();

        short8 a_h[4], a_l[4], b_h[4], b_l[4];
#pragma unroll
        for (int i = 0; i < 4; ++i) {
            a_h[i] = *(const short8*)&Ah[wm + i * 16 + m16][quad * 8];
            a_l[i] = *(const short8*)&Al[wm + i * 16 + m16][quad * 8];
            b_h[i] = *(const short8*)&Bh[wn + i * 16 + m16][quad * 8];
            b_l[i] = *(const short8*)&Bl[wn + i * 16 + m16][quad * 8];
        }
#pragma unroll
        for (int i = 0; i < 4; ++i)
#pragma unroll
            for (int j = 0; j < 4; ++j) {
                acc[i][j] = __builtin_amdgcn_mfma_f32_16x16x32_bf16(
                    a_h[i], b_h[j], acc[i][j], 0, 0, 0);
                acc[i][j] = __builtin_amdgcn_mfma_f32_16x16x32_bf16(
                    a_l[i], b_h[j], acc[i][j], 0, 0, 0);
                acc[i][j] = __builtin_amdgcn_mfma_f32_16x16x32_bf16(
                    a_h[i], b_l[j], acc[i][j], 0, 0, 0);
            }
    }

    // Epilogue. C/D layout: col = lane&15, row = quad*4 + reg [m89/m91 verified]
#pragma unroll
    for (int i = 0; i < 4; ++i)
#pragma unroll
        for (int j = 0; j < 4; ++j) {
            const int col = n0 + wn + j * 16 + m16;
#pragma unroll
            for (int r = 0; r < 4; ++r) {
                const int row = m0 + wm + i * 16 + quad * 4 + r;
                const size_t off = (size_t)row * ldc + col;
                const float v = acc[i][j][r];
                if (EPI == EPI_NONE) C[off] = v;
                else                 C[off] = C[off] * siluf(v);
            }
        }
}

// ---------------- fp32 GEMM (kept for the small N=64 x-proj) -------------------
#define TBM 64
#define TBN 64
#define TBK 16

__global__ __launch_bounds__(256)
void gemm_atb(const float* __restrict__ A, int lda,
              const float* __restrict__ B, int ldb,
              float* __restrict__ C, int ldc,
              int K) {
    __shared__ float As[TBM][TBK + 1];
    __shared__ float Bs[TBN][TBK + 1];

    const int tid = threadIdx.x;
    const int tx = tid & 15;
    const int ty = tid >> 4;
    const int m0 = blockIdx.y * TBM;
    const int n0 = blockIdx.x * TBN;

    const int lr = tid >> 2;
    const int lc = (tid & 3) * 4;

    float acc[4][4];
#pragma unroll
    for (int i = 0; i < 4; ++i)
#pragma unroll
        for (int j = 0; j < 4; ++j) acc[i][j] = 0.0f;

    for (int k0 = 0; k0 < K; k0 += TBK) {
        const float4 av = *(const float4*)(A + (size_t)(m0 + lr) * lda + k0 + lc);
        const float4 bv = *(const float4*)(B + (size_t)(n0 + lr) * ldb + k0 + lc);
        As[lr][lc + 0] = av.x; As[lr][lc + 1] = av.y;
        As[lr][lc + 2] = av.z; As[lr][lc + 3] = av.w;
        Bs[lr][lc + 0] = bv.x; Bs[lr][lc + 1] = bv.y;
        Bs[lr][lc + 2] = bv.z; Bs[lr][lc + 3] = bv.w;
        __syncthreads();

#pragma unroll
        for (int kk = 0; kk < TBK; ++kk) {
            float a[4], b[4];
#pragma unroll
            for (int i = 0; i < 4; ++i) a[i] = As[ty * 4 + i][kk];
#pragma unroll
            for (int j = 0; j < 4; ++j) b[j] = Bs[tx * 4 + j][kk];
#pragma unroll
            for (int i = 0; i < 4; ++i)
#pragma unroll
                for (int j = 0; j < 4; ++j) acc[i][j] += a[i] * b[j];
        }
        __syncthreads();
    }

#pragma unroll
    for (int i = 0; i < 4; ++i) {
        const int r = m0 + ty * 4 + i;
#pragma unroll
        for (int j = 0; j < 4; ++j) {
            const int c = n0 + tx * 4 + j;
            C[(size_t)r * ldc + c] = acc[i][j];
        }
    }
}

// ---------------- conv halo save: raw x at split boundaries --------------------
// Runs BEFORE conv overwrites xs. Saves x[sp*CTS-3 .. sp*CTS-1] for sp=1..7.
__global__ __launch_bounds__(256)
void halo_save(const float* __restrict__ xs, float* __restrict__ halo) {
    const int idx = blockIdx.x * 256 + threadIdx.x;  // NBC*(CSPL-1)*3*DINNER
    if (idx >= NBC * (CSPL - 1) * 3 * DINNER) return;
    const int d  = idx & (DINNER - 1);
    int r = idx >> 10;                   // 0 .. 32*7*3-1
    const int j  = r % 3;  r /= 3;       // halo element 0..2
    const int sp = (r % (CSPL - 1)) + 1; // split 1..7
    const int b  = r / (CSPL - 1);
    halo[(((size_t)b * CSPL + sp) * 3 + j) * DINNER + d] =
        xs[((size_t)b * SEQ + sp * CTS - 3 + j) * DINNER + d];
}

// ---------------- depthwise causal conv (w=4) + bias + SiLU, in place, split ---
// Each block owns a disjoint t-range [sp*CTS, (sp+1)*CTS) of one sequence.
// Cross-split halo comes from the halo buffer (raw x saved above) -> no
// read-after-overwrite race between blocks. 8x more blocks than the serial
// version (1024 vs 128 -> all CUs busy).
__global__ __launch_bounds__(256)
void conv_split_silu(float* __restrict__ xs,
                     const float* __restrict__ conv_w,
                     const float* __restrict__ conv_b,
                     const float* __restrict__ halo) {
    const int gid = blockIdx.x * 256 + threadIdx.x;  // NBC*CSPL*DINNER threads
    const int d  = gid & (DINNER - 1);
    const int sp = (gid >> 10) & (CSPL - 1);
    const int b  = gid >> 13;
    const float w0 = conv_w[d * DCONV + 0];
    const float w1 = conv_w[d * DCONV + 1];
    const float w2 = conv_w[d * DCONV + 2];
    const float w3 = conv_w[d * DCONV + 3];
    const float cb = conv_b[d];
    float x0, x1, x2;
    if (sp == 0) {
        x0 = 0.0f; x1 = 0.0f; x2 = 0.0f;
    } else {
        const float* hsrc = halo + (((size_t)b * CSPL + sp) * 3) * DINNER + d;
        x0 = hsrc[0];
        x1 = hsrc[DINNER];
        x2 = hsrc[2 * DINNER];
    }
    size_t p = ((size_t)b * SEQ + sp * CTS) * DINNER + d;
    for (int t = 0; t < CTS; ++t, p += DINNER) {
        const float xv = xs[p];
        const float acc = cb + w0 * x0 + w1 * x1 + w2 * x2 + w3 * xv;
        xs[p] = siluf(acc);
        x0 = x1; x1 = x2; x2 = xv;
    }
}

// ---------------- chunked selective scan (2 passes, write-once scratch) --------
// ps per (chunk,b,d): slot 0 = sum(dt) over chunk (log-domain decay; the
// chunk's P[s] = exp(a[s]*dtsum) is reconstructed at compose time), slots
// 1..16 = end-of-chunk state S[s]. 17 slots -> GCH=16 fits in d_out.
// a[s] structure: A_log = log(arange(1..16)) => a[s] ~= -(s+1). When that
// holds (checked per-thread, generic fallback kept), dA[s] = E^(s+1) with
// E = exp(dtv*a[0]): 1 trans + 15 muls instead of 16 trans per step.
__device__ __forceinline__ size_t ps_idx(int c, int b, int slot, int d) {
    return ((size_t)(c * NBC + b) * PSLOT + slot) * DINNER + d;
}

template <int PASS>
__global__ __launch_bounds__(256)
void scan_chunk_kernel(float* __restrict__ xs,        // in: conv'd x; out(P1): y+x*D
                       const float* __restrict__ x_dbl,
                       const float* __restrict__ W_dt,
                       const float* __restrict__ b_dt,
                       const float* __restrict__ A_log,
                       const float* __restrict__ Dp,
                       float* __restrict__ ps) {
    const int tid = threadIdx.x;
    const int c  = blockIdx.x & (GCH - 1);
    const int dg = (blockIdx.x >> 4) & 3;
    const int b  = blockIdx.x >> 6;
    const int d  = (dg << 8) + tid;

    // Chunk GCH-1's (dtsum,S) is never consumed (PASS1 reads only j < c).
    if (PASS == 0 && c == GCH - 1) return;

    float wdt[DTRANK];
#pragma unroll
    for (int k = 0; k < DTRANK; ++k) wdt[k] = W_dt[d * DTRANK + k];
    const float bdt = b_dt[d];
    const float Dv = Dp[d];

    float a[DSTATE], h[DSTATE];
    bool afast = true;
#pragma unroll
    for (int s = 0; s < DSTATE; ++s) {
        a[s] = -expf(A_log[d * DSTATE + s]);
        afast = afast && (fabsf(a[s] + (float)(s + 1)) <= 3e-3f * (float)(s + 1));
    }

    float dtsum = 0.0f;
#pragma unroll
    for (int s = 0; s < DSTATE; ++s) h[s] = 0.0f;

    if (PASS == 1) {
        // Fused chunk prefix: h_in = compose(chunks 0..c-1).
        for (int j = 0; j < c; ++j) {       // wave-uniform trip count
            const float dsj = ps[ps_idx(j, b, 0, d)];
            if (afast) {
                const float F = __expf(dsj * a[0]);
                float P = F;                  // P = F^(s+1)
#pragma unroll
                for (int s = 0; s < DSTATE; ++s) {
                    h[s] = fmaf(P, h[s], ps[ps_idx(j, b, 1 + s, d)]);
                    P *= F;
                }
            } else {
#pragma unroll
                for (int s = 0; s < DSTATE; ++s)
                    h[s] = fmaf(__expf(dsj * a[s]), h[s],
                                ps[ps_idx(j, b, 1 + s, d)]);
            }
        }
    }

    __shared__ float bc[SUB][XD];
    const size_t brow = (size_t)b * SEQ + (size_t)c * CLEN;

    for (int t0 = 0; t0 < CLEN; t0 += SUB) {
        __syncthreads();
        if (PASS == 0) {
            // stage only dt(32)+B(16) = 48 cols
            for (int e = tid; e < SUB * 12; e += 256) {
                const int tt = e / 12;
                const int c4 = (e - tt * 12) * 4;
                const float4 v = *(const float4*)(x_dbl + (brow + t0 + tt) * XD + c4);
                bc[tt][c4 + 0] = v.x; bc[tt][c4 + 1] = v.y;
                bc[tt][c4 + 2] = v.z; bc[tt][c4 + 3] = v.w;
            }
        } else {
            for (int e = tid; e < SUB * 16; e += 256) {
                const int tt = e >> 4;
                const int c4 = (e & 15) * 4;
                const float4 v = *(const float4*)(x_dbl + (brow + t0 + tt) * XD + c4);
                bc[tt][c4 + 0] = v.x; bc[tt][c4 + 1] = v.y;
                bc[tt][c4 + 2] = v.z; bc[tt][c4 + 3] = v.w;
            }
        }
        __syncthreads();

        for (int tt = 0; tt < SUB; ++tt) {
            // dt GEMV: float4 LDS reads (ds_read_b128), 4 indep fma chains
            float g0 = 0.0f, g1 = 0.0f, g2 = 0.0f, g3 = 0.0f;
#pragma unroll
            for (int k = 0; k < DTRANK; k += 4) {
                const float4 q = *(const float4*)&bc[tt][k];
                g0 = fmaf(q.x, wdt[k + 0], g0);
                g1 = fmaf(q.y, wdt[k + 1], g1);
                g2 = fmaf(q.z, wdt[k + 2], g2);
                g3 = fmaf(q.w, wdt[k + 3], g3);
            }
            const float dtv = softplus_fast(bdt + ((g0 + g1) + (g2 + g3)));
            if (PASS == 0) dtsum += dtv;

            union F4 { float4 v; float f[4]; };
            F4 Bv[4], Cv[4];
#pragma unroll
            for (int q = 0; q < 4; ++q)
                Bv[q].v = *(const float4*)&bc[tt][DTRANK + q * 4];
            if (PASS == 1) {
#pragma unroll
                for (int q = 0; q < 4; ++q)
                    Cv[q].v = *(const float4*)&bc[tt][DTRANK + DSTATE + q * 4];
            }

            const size_t row = brow + t0 + tt;
            const float xv = xs[row * DINNER + d];
            const float pre = dtv * xv;
            float y0 = 0.0f, y1 = 0.0f;
            if (afast) {
                const float E = __expf(dtv * a[0]);
                float dA = E;                 // dA = E^(s+1)
#pragma unroll
                for (int s = 0; s < DSTATE; ++s) {
                    h[s] = fmaf(dA, h[s], pre * Bv[s >> 2].f[s & 3]);
                    if (PASS == 1) {
                        if (s & 1) y1 = fmaf(h[s], Cv[s >> 2].f[s & 3], y1);
                        else       y0 = fmaf(h[s], Cv[s >> 2].f[s & 3], y0);
                    }
                    dA *= E;
                }
            } else {
#pragma unroll
                for (int s = 0; s < DSTATE; ++s) {
                    const float dA = __expf(dtv * a[s]);
                    h[s] = fmaf(dA, h[s], pre * Bv[s >> 2].f[s & 3]);
                    if (PASS == 1) {
                        if (s & 1) y1 = fmaf(h[s], Cv[s >> 2].f[s & 3], y1);
                        else       y0 = fmaf(h[s], Cv[s >> 2].f[s & 3], y0);
                    }
                }
            }
            if (PASS == 1) xs[row * DINNER + d] = fmaf(xv, Dv, y0 + y1);
        }
    }

    if (PASS == 0) {
        ps[ps_idx(c, b, 0, d)] = dtsum;
#pragma unroll
        for (int s = 0; s < DSTATE; ++s)
            ps[ps_idx(c, b, 1 + s, d)] = h[s];
    }
}

// ---------------- launch ----------------
// Workspace ws: xs = NROWS*DINNER floats = 128 MiB (x -> conv'd -> y, in place);
// optional +2 MiB tail for pre-split W_out (checked against ws_size at launch).
// d_out (64 MiB) doubles as scratch before the final GEMM:
//   [ 0,  8 MiB)  x_dbl   2,097,152 floats
//   [ 8, ~42 MiB) ps      GCH*NBC*PSLOT*DINNER = 8,912,896 floats
//   [44, 48 MiB)  W2in    pre-split W_in (needed through step 5)
//   [48, 51 MiB)  halo    conv boundary values
// Step 6 overwrites all of d_out; everything it reads lives in ws / d_in.
// Every scratch region is fully rewritten each launch (graph-replay safe).
extern "C" void kernel_launch(void* const* d_in, const int* in_sizes, int n_in,
                              void* d_out, int out_size, void* d_ws, size_t ws_size,
                              hipStream_t stream) {
    const float* x       = (const float*)d_in[0];
    const float* W_in    = (const float*)d_in[1];
    const float* conv_w  = (const float*)d_in[2];
    const float* conv_b  = (const float*)d_in[3];
    const float* W_xproj = (const float*)d_in[4];
    const float* W_dt    = (const float*)d_in[5];
    const float* b_dt    = (const float*)d_in[6];
    const float* A_log   = (const float*)d_in[7];
    const float* Dp      = (const float*)d_in[8];
    const float* W_out   = (const float*)d_in[9];
    float* out = (float*)d_out;

    float* xs    = (float*)d_ws;             // in-place pipeline buffer
    float* x_dbl = out;                      // d_out[0 .. 2M floats)
    float* ps    = out + (size_t)NROWS * XD; // d_out[2M .. 10.91M floats)
    unsigned char* w2in = (unsigned char*)(out + 11534336);  // 44 MiB offset
    float* halo  = out + 12582912;                            // 48 MiB offset

    const size_t xs_bytes = (size_t)NROWS * DINNER * 4;      // 128 MiB
    unsigned char* w2out = (unsigned char*)d_ws + xs_bytes;  // 2 MiB split W_out
    const bool have_wout = ws_size >= xs_bytes + (size_t)DMODEL * (DINNER / 32) * 128;

    dim3 blk(256);

    // 0. prepass: split weights -> blocked bf16 hi/lo (tiny; ~6 MiB traffic)
    split_w<<<(2048 * 16) / 256, blk, 0, stream>>>(W_in, w2in, 2048, DMODEL);
    if (have_wout)
        split_w<<<(512 * 32) / 256, blk, 0, stream>>>(W_out, w2out, DMODEL, DINNER);

    // 1. xs = u @ W_in[0:1024]^T   (M=32768, N=1024, K=512)  [B pre-split]
    gemm_split<true, EPI_NONE><<<dim3(DINNER / 128, NROWS / 128), blk, 0, stream>>>(
        x, DMODEL, nullptr, w2in, 0, xs, DINNER, DMODEL);

    // 2a. save raw x at conv split boundaries (before any conv write)
    halo_save<<<(NBC * (CSPL - 1) * 3 * DINNER) / 256, blk, 0, stream>>>(xs, halo);
    // 2b. depthwise conv + bias + SiLU, in place, t-split 8x
    conv_split_silu<<<NBC * CSPL * DINNER / 256, blk, 0, stream>>>(
        xs, conv_w, conv_b, halo);

    // 3. x_dbl = xs @ W_xproj^T    (M=32768, N=64, K=1024) -> stashed in d_out
    gemm_atb<<<dim3(XD / TBN, NROWS / TBM), blk, 0, stream>>>(
        xs, DINNER, W_xproj, DINNER, x_dbl, XD, DINNER);

    // 4a. chunk-local (dtsum, S) -> ps (write-once; chunk GCH-1 early-exits)
    scan_chunk_kernel<0><<<NBC * 4 * GCH, blk, 0, stream>>>(
        xs, x_dbl, W_dt, b_dt, A_log, Dp, ps);
    // 4b. fused prefix + re-walk chunks, write ungated y + x*D over xs
    scan_chunk_kernel<1><<<NBC * 4 * GCH, blk, 0, stream>>>(
        xs, x_dbl, W_dt, b_dt, A_log, Dp, ps);

    // 5. z-gate: z = u @ W_in[1024:2048]^T, xs *= silu(z)  [B pre-split]
    gemm_split<true, EPI_GATE><<<dim3(DINNER / 128, NROWS / 128), blk, 0, stream>>>(
        x, DMODEL, nullptr, w2in + (size_t)1024 * 16 * 128, 0, xs, DINNER, DMODEL);

    // 6. out = y @ W_out^T         (M=32768, N=512, K=1024)
    if (have_wout)
        gemm_split<true, EPI_NONE><<<dim3(DMODEL / 128, NROWS / 128), blk, 0, stream>>>(
            xs, DINNER, nullptr, w2out, 0, out, DMODEL, DINNER);
    else
        gemm_split<false, EPI_NONE><<<dim3(DMODEL / 128, NROWS / 128), blk, 0, stream>>>(
            xs, DINNER, W_out, nullptr, DINNER, out, DMODEL, DINNER);
}